// Round 1
// baseline (1221.801 us; speedup 1.0000x reference)
//
#include <hip/hip_runtime.h>
#include <stdint.h>

typedef unsigned short u16;
using short8 = __attribute__((ext_vector_type(8))) short;
using f32x4  = __attribute__((ext_vector_type(4))) float;

#define S_LEN 2048
#define NBATCH 2
#define NH 32
#define NKV 8
#define HD 128
#define DIM 4096
#define NQ 4096      // NH*HD
#define NKVD 1024    // NKV*HD

__device__ __forceinline__ float b2f(u16 u) {
  union { unsigned u32; float f; } x; x.u32 = ((unsigned)u) << 16; return x.f;
}
__device__ __forceinline__ u16 f2b(float f) {
  union { float f; unsigned u32; } x; x.f = f;
  unsigned lsb = (x.u32 >> 16) & 1u;
  x.u32 += 0x7fffu + lsb;            // round-to-nearest-even
  return (u16)(x.u32 >> 16);
}

// ---------------- transpose + cast: in [K][N] fp32 -> out [N][K] bf16 ----------------
__global__ __launch_bounds__(256) void transpose_cast(const float* __restrict__ in,
                                                      u16* __restrict__ out,
                                                      int K, int N) {
  __shared__ float tile[32][33];
  int n0 = blockIdx.x * 32, k0 = blockIdx.y * 32;
  int tx = threadIdx.x, ty = threadIdx.y;   // block (32,8)
#pragma unroll
  for (int j = 0; j < 4; ++j)
    tile[ty + j * 8][tx] = in[(size_t)(k0 + ty + j * 8) * N + n0 + tx];
  __syncthreads();
#pragma unroll
  for (int j = 0; j < 4; ++j)
    out[(size_t)(n0 + ty + j * 8) * K + k0 + tx] = f2b(tile[tx][ty + j * 8]);
}

// ---------------- cast x fp32 -> bf16 ----------------
__global__ __launch_bounds__(256) void cast_x(const float* __restrict__ in,
                                              u16* __restrict__ out, int n4) {
  int i = blockIdx.x * 256 + threadIdx.x;
  if (i >= n4) return;
  float4 v = reinterpret_cast<const float4*>(in)[i];
  ushort4 u;
  u.x = f2b(v.x); u.y = f2b(v.y); u.z = f2b(v.z); u.w = f2b(v.w);
  reinterpret_cast<ushort4*>(out)[i] = u;
}

// ---------------- bt-GEMM: C[M=4096][N] = A[4096][4096] * Bt[N][4096]^T ----------------
// mode 0: scatter into Qb/Kb/Vt (with V transposed). mode 1: fp32 row-major out.
__global__ __launch_bounds__(256, 2) void gemm_bt(const u16* __restrict__ A,
                                                  const u16* __restrict__ Bt,
                                                  int N, int mode,
                                                  float* __restrict__ out,
                                                  u16* __restrict__ Qb,
                                                  u16* __restrict__ Kb,
                                                  u16* __restrict__ Vt) {
  const int K = 4096;
  __shared__ __align__(16) u16 As[128][40];
  __shared__ __align__(16) u16 Bs[128][40];
  int tid  = threadIdx.x;
  int m0   = blockIdx.y * 128, n0 = blockIdx.x * 128;
  int lane = tid & 63, w = tid >> 6;
  int wr   = w >> 1, wc = w & 1;
  int ml   = lane & 15, quad = lane >> 4;

  f32x4 acc[4][4] = {};

  for (int k0 = 0; k0 < K; k0 += 32) {
    __syncthreads();
#pragma unroll
    for (int p = 0; p < 2; ++p) {
      int c = tid + p * 256;
      int row = c >> 2, c8 = c & 3;
      uint4 va = *reinterpret_cast<const uint4*>(A + (size_t)(m0 + row) * K + k0 + c8 * 8);
      *reinterpret_cast<uint4*>(&As[row][c8 * 8]) = va;
      uint4 vb = *reinterpret_cast<const uint4*>(Bt + (size_t)(n0 + row) * K + k0 + c8 * 8);
      *reinterpret_cast<uint4*>(&Bs[row][c8 * 8]) = vb;
    }
    __syncthreads();
    short8 af[4], bfr[4];
#pragma unroll
    for (int mi = 0; mi < 4; ++mi)
      af[mi] = *reinterpret_cast<const short8*>(&As[wr * 64 + mi * 16 + ml][quad * 8]);
#pragma unroll
    for (int ni = 0; ni < 4; ++ni)
      bfr[ni] = *reinterpret_cast<const short8*>(&Bs[wc * 64 + ni * 16 + ml][quad * 8]);
#pragma unroll
    for (int mi = 0; mi < 4; ++mi)
#pragma unroll
      for (int ni = 0; ni < 4; ++ni)
        acc[mi][ni] = __builtin_amdgcn_mfma_f32_16x16x32_bf16(af[mi], bfr[ni], acc[mi][ni], 0, 0, 0);
  }

#pragma unroll
  for (int mi = 0; mi < 4; ++mi) {
#pragma unroll
    for (int ni = 0; ni < 4; ++ni) {
#pragma unroll
      for (int r = 0; r < 4; ++r) {
        int row = m0 + wr * 64 + mi * 16 + quad * 4 + r;
        int col = n0 + wc * 64 + ni * 16 + ml;
        float v = acc[mi][ni][r];
        if (mode == 1) {
          out[(size_t)row * N + col] = v;
        } else {
          int b = row >> 11, s = row & (S_LEN - 1);
          if (col < NQ) {
            int h = col >> 7, d = col & 127;
            Qb[((size_t)((b * NH + h) * S_LEN + s)) * HD + d] = f2b(v);
          } else if (col < NQ + NKVD) {
            int cc = col - NQ; int h = cc >> 7, d = cc & 127;
            Kb[((size_t)((b * NKV + h) * S_LEN + s)) * HD + d] = f2b(v);
          } else {
            int cc = col - NQ - NKVD; int h = cc >> 7, d = cc & 127;
            Vt[((size_t)((b * NKV + h) * HD + d)) * S_LEN + s] = f2b(v);
          }
        }
      }
    }
  }
}

// ---------------- RoPE in-place on [.., s, 64 pairs] bf16 ----------------
__global__ __launch_bounds__(256) void rope_ip(u16* __restrict__ X, int npairs) {
  int idx = blockIdx.x * 256 + threadIdx.x;
  if (idx >= npairs) return;
  int i = idx & 63;
  int s = (idx >> 6) & (S_LEN - 1);
  float inv = __expf(-0.2050369278939421f * (float)i);  // ln(500000)/64
  float ang = (float)s * inv;
  float sn, cs;
  sincosf(ang, &sn, &cs);
  ushort2 pr = reinterpret_cast<ushort2*>(X)[idx];
  float a = b2f(pr.x), b = b2f(pr.y);
  ushort2 o;
  o.x = f2b(a * cs - b * sn);
  o.y = f2b(a * sn + b * cs);
  reinterpret_cast<ushort2*>(X)[idx] = o;
}

// ---------------- flash attention: 64 q rows/block, kv tiles of 64 ----------------
__global__ __launch_bounds__(256, 2) void flash(const u16* __restrict__ Qb,
                                                const u16* __restrict__ Kb,
                                                const u16* __restrict__ Vt,
                                                u16* __restrict__ AO) {
  __shared__ __align__(16) u16 Qs[64][136];
  __shared__ __align__(16) u16 Ks[64][136];
  __shared__ __align__(16) u16 Vs[128][72];
  __shared__ __align__(16) u16 Ps[4][16][72];

  int tid  = threadIdx.x;
  int lane = tid & 63, w = tid >> 6;
  int ml   = lane & 15, quad = lane >> 4;
  int q_tile = blockIdx.x, h = blockIdx.y, b = blockIdx.z;
  int hkv = h >> 2;
  int q0  = q_tile * 64;
  const u16* Qh = Qb + ((size_t)(b * NH + h) * S_LEN) * HD;
  const u16* Kh = Kb + ((size_t)(b * NKV + hkv) * S_LEN) * HD;
  const u16* Vh = Vt + ((size_t)(b * NKV + hkv) * HD) * S_LEN;

  for (int c = tid; c < 1024; c += 256) {
    int row = c >> 4, c8 = c & 15;
    *reinterpret_cast<uint4*>(&Qs[row][c8 * 8]) =
        *(reinterpret_cast<const uint4*>(Qh + (size_t)(q0 + row) * HD) + c8);
  }

  f32x4 o[8] = {};
  float mrow[4] = {-1e30f, -1e30f, -1e30f, -1e30f};
  float lrow[4] = {0.f, 0.f, 0.f, 0.f};
  const float scale = 0.08838834764831845f;  // 1/sqrt(128)
  const float L2E   = 1.4426950408889634f;

  int ntile = q_tile + 1;
  for (int it = 0; it < ntile; ++it) {
    int kv0 = it * 64;
    __syncthreads();
    for (int c = tid; c < 1024; c += 256) {
      int row = c >> 4, c8 = c & 15;
      *reinterpret_cast<uint4*>(&Ks[row][c8 * 8]) =
          *(reinterpret_cast<const uint4*>(Kh + (size_t)(kv0 + row) * HD) + c8);
    }
    for (int c = tid; c < 1024; c += 256) {
      int d = c >> 3, c8 = c & 7;
      *reinterpret_cast<uint4*>(&Vs[d][c8 * 8]) =
          *(reinterpret_cast<const uint4*>(Vh + (size_t)d * S_LEN + kv0) + c8);
    }
    __syncthreads();

    // S = Q K^T for this wave's 16-row strip
    f32x4 sc[4] = {};
#pragma unroll
    for (int ks = 0; ks < 4; ++ks) {
      short8 af = *reinterpret_cast<const short8*>(&Qs[w * 16 + ml][ks * 32 + quad * 8]);
#pragma unroll
      for (int nt = 0; nt < 4; ++nt) {
        short8 bf = *reinterpret_cast<const short8*>(&Ks[nt * 16 + ml][ks * 32 + quad * 8]);
        sc[nt] = __builtin_amdgcn_mfma_f32_16x16x32_bf16(af, bf, sc[nt], 0, 0, 0);
      }
    }

    bool diag = (it == q_tile);
    int qgr = q0 + w * 16 + quad * 4;
#pragma unroll
    for (int nt = 0; nt < 4; ++nt) {
      int kg = kv0 + nt * 16 + ml;
#pragma unroll
      for (int r = 0; r < 4; ++r) {
        float v = sc[nt][r] * scale;
        if (diag && kg > qgr + r) v = -1e30f;
        sc[nt][r] = v;
      }
    }

    float rm[4];
#pragma unroll
    for (int r = 0; r < 4; ++r) {
      float m_ = fmaxf(fmaxf(sc[0][r], sc[1][r]), fmaxf(sc[2][r], sc[3][r]));
      m_ = fmaxf(m_, __shfl_xor(m_, 1, 64));
      m_ = fmaxf(m_, __shfl_xor(m_, 2, 64));
      m_ = fmaxf(m_, __shfl_xor(m_, 4, 64));
      m_ = fmaxf(m_, __shfl_xor(m_, 8, 64));
      rm[r] = m_;
    }
    float alpha[4];
#pragma unroll
    for (int r = 0; r < 4; ++r) {
      float mn = fmaxf(mrow[r], rm[r]);
      alpha[r] = exp2f((mrow[r] - mn) * L2E);
      mrow[r]  = mn;
    }
    float rs[4] = {0.f, 0.f, 0.f, 0.f};
#pragma unroll
    for (int nt = 0; nt < 4; ++nt)
#pragma unroll
      for (int r = 0; r < 4; ++r) {
        float p = exp2f((sc[nt][r] - mrow[r]) * L2E);
        sc[nt][r] = p;
        rs[r] += p;
      }
#pragma unroll
    for (int r = 0; r < 4; ++r) {
      float s_ = rs[r];
      s_ += __shfl_xor(s_, 1, 64);
      s_ += __shfl_xor(s_, 2, 64);
      s_ += __shfl_xor(s_, 4, 64);
      s_ += __shfl_xor(s_, 8, 64);
      lrow[r] = lrow[r] * alpha[r] + s_;
    }
    // P (C-layout) -> LDS (A-layout source)
#pragma unroll
    for (int nt = 0; nt < 4; ++nt)
#pragma unroll
      for (int r = 0; r < 4; ++r)
        Ps[w][quad * 4 + r][nt * 16 + ml] = f2b(sc[nt][r]);
    __syncthreads();
    // rescale O
#pragma unroll
    for (int dt = 0; dt < 8; ++dt)
#pragma unroll
      for (int r = 0; r < 4; ++r) o[dt][r] *= alpha[r];
    // O += P V
#pragma unroll
    for (int ks = 0; ks < 2; ++ks) {
      short8 ap = *reinterpret_cast<const short8*>(&Ps[w][ml][ks * 32 + quad * 8]);
#pragma unroll
      for (int dt = 0; dt < 8; ++dt) {
        short8 bv = *reinterpret_cast<const short8*>(&Vs[dt * 16 + ml][ks * 32 + quad * 8]);
        o[dt] = __builtin_amdgcn_mfma_f32_16x16x32_bf16(ap, bv, o[dt], 0, 0, 0);
      }
    }
  }

  size_t row_base = (size_t)(b * S_LEN + q0 + w * 16 + quad * 4);
#pragma unroll
  for (int dt = 0; dt < 8; ++dt) {
    int col = h * HD + dt * 16 + ml;
#pragma unroll
    for (int r = 0; r < 4; ++r) {
      float v = o[dt][r] / lrow[r];
      AO[(row_base + r) * (size_t)DIM + col] = f2b(v);
    }
  }
}

extern "C" void kernel_launch(void* const* d_in, const int* in_sizes, int n_in,
                              void* d_out, int out_size, void* d_ws, size_t ws_size,
                              hipStream_t stream) {
  const float* x  = (const float*)d_in[0];
  const float* wq = (const float*)d_in[1];
  const float* wk = (const float*)d_in[2];
  const float* wv = (const float*)d_in[3];
  const float* wo = (const float*)d_in[4];
  float* out = (float*)d_out;
  char* ws = (char*)d_ws;

  // workspace layout (bytes), 128 MiB total; AO aliases Xb, Wot aliases Wqt
  u16* Wqt = (u16*)(ws + 0);          // [4096][4096] also Wot later
  u16* Wkt = (u16*)(ws + 33554432);   // [1024][4096]
  u16* Wvt = (u16*)(ws + 41943040);   // [1024][4096]
  u16* Xb  = (u16*)(ws + 50331648);   // [4096][4096] also AO later
  u16* Qb  = (u16*)(ws + 83886080);   // [2][32][2048][128]
  u16* Kb  = (u16*)(ws + 117440512);  // [2][8][2048][128]
  u16* Vt  = (u16*)(ws + 125829120);  // [2][8][128][2048]

  transpose_cast<<<dim3(128, 128), dim3(32, 8), 0, stream>>>(wq, Wqt, 4096, 4096);
  transpose_cast<<<dim3(32, 128),  dim3(32, 8), 0, stream>>>(wk, Wkt, 4096, 1024);
  transpose_cast<<<dim3(32, 128),  dim3(32, 8), 0, stream>>>(wv, Wvt, 4096, 1024);
  cast_x<<<16384, 256, 0, stream>>>(x, Xb, 4194304);

  // QKV projection: Bt = [Wqt|Wkt|Wvt] contiguous [6144][4096]
  gemm_bt<<<dim3(48, 32), 256, 0, stream>>>(Xb, Wqt, 6144, 0, nullptr, Qb, Kb, Vt);

  rope_ip<<<32768, 256, 0, stream>>>(Qb, 8388608);
  rope_ip<<<8192, 256, 0, stream>>>(Kb, 2097152);

  // wo^T into the (now free) Wqt region
  transpose_cast<<<dim3(128, 128), dim3(32, 8), 0, stream>>>(wo, Wqt, 4096, 4096);

  // flash attention -> AO (aliases Xb region; Xb no longer needed)
  flash<<<dim3(32, 32, 2), 256, 0, stream>>>(Qb, Kb, Vt, Xb);

  // out = AO @ wo
  gemm_bt<<<dim3(32, 32), 256, 0, stream>>>(Xb, Wqt, 4096, 1, out, nullptr, nullptr, nullptr);
}

// Round 2
// 891.259 us; speedup vs baseline: 1.3709x; 1.3709x over previous
//
#include <hip/hip_runtime.h>
#include <stdint.h>

typedef unsigned short u16;
using short8 = __attribute__((ext_vector_type(8))) short;
using f32x4  = __attribute__((ext_vector_type(4))) float;

#define S_LEN 2048
#define NH 32
#define NKV 8
#define HD 128
#define DIM 4096
#define NQ 4096
#define NKVD 1024

typedef __attribute__((address_space(1))) unsigned int uGLB;
typedef __attribute__((address_space(3))) unsigned int uLDS;

__device__ __forceinline__ void g2l16(const u16* g, u16* l) {
  __builtin_amdgcn_global_load_lds((const uGLB*)g, (uLDS*)l, 16, 0, 0);
}

__device__ __forceinline__ float b2f(u16 u) {
  union { unsigned u32; float f; } x; x.u32 = ((unsigned)u) << 16; return x.f;
}
__device__ __forceinline__ u16 f2b(float f) {
  union { float f; unsigned u32; } x; x.f = f;
  unsigned lsb = (x.u32 >> 16) & 1u;
  x.u32 += 0x7fffu + lsb;
  return (u16)(x.u32 >> 16);
}

// ---------------- transpose + cast: in [K][N] fp32 -> out [N][K] bf16 ----------------
__global__ __launch_bounds__(256) void transpose_cast(const float* __restrict__ in,
                                                      u16* __restrict__ out,
                                                      int K, int N) {
  __shared__ float tile[32][33];
  int n0 = blockIdx.x * 32, k0 = blockIdx.y * 32;
  int tx = threadIdx.x, ty = threadIdx.y;
#pragma unroll
  for (int j = 0; j < 4; ++j)
    tile[ty + j * 8][tx] = in[(size_t)(k0 + ty + j * 8) * N + n0 + tx];
  __syncthreads();
#pragma unroll
  for (int j = 0; j < 4; ++j)
    out[(size_t)(n0 + ty + j * 8) * K + k0 + tx] = f2b(tile[tx][ty + j * 8]);
}

__global__ __launch_bounds__(256) void cast_x(const float* __restrict__ in,
                                              u16* __restrict__ out, int n4) {
  int i = blockIdx.x * 256 + threadIdx.x;
  if (i >= n4) return;
  float4 v = reinterpret_cast<const float4*>(in)[i];
  ushort4 u;
  u.x = f2b(v.x); u.y = f2b(v.y); u.z = f2b(v.z); u.w = f2b(v.w);
  reinterpret_cast<ushort4*>(out)[i] = u;
}

// ---------------- bt-GEMM with global_load_lds staging (m97 structure) ----------------
__global__ __launch_bounds__(256, 2) void gemm_bt(const u16* __restrict__ A,
                                                  const u16* __restrict__ Bt,
                                                  int N, int mode,
                                                  float* __restrict__ out,
                                                  u16* __restrict__ Qb,
                                                  u16* __restrict__ Kb,
                                                  u16* __restrict__ Vt) {
  const int K = 4096;
  __shared__ __align__(16) u16 As[128 * 32];   // swizzled: chunk' = chunk ^ ((row>>1)&3)
  __shared__ __align__(16) u16 Bs[128 * 32];
  int tid  = threadIdx.x;
  int m0   = blockIdx.y * 128, n0 = blockIdx.x * 128;
  int lane = tid & 63, w = tid >> 6;
  int wr   = w >> 1, wc = w & 1;
  int ml   = lane & 15, quad = lane >> 4;

  f32x4 acc[4][4] = {};

  for (int k0 = 0; k0 < K; k0 += 32) {
    __syncthreads();
#pragma unroll
    for (int p = 0; p < 2; ++p) {
      int slot = w * 128 + p * 64 + lane;
      int row = slot >> 2, ch = slot & 3;
      int src = ch ^ ((row >> 1) & 3);
      g2l16(A + (size_t)(m0 + row) * K + k0 + src * 8, &As[(w * 128 + p * 64) * 8]);
      g2l16(Bt + (size_t)(n0 + row) * K + k0 + src * 8, &Bs[(w * 128 + p * 64) * 8]);
    }
    __syncthreads();
    short8 af[4], bfr[4];
#pragma unroll
    for (int mi = 0; mi < 4; ++mi) {
      int row = wr * 64 + mi * 16 + ml;
      int ch = quad ^ ((row >> 1) & 3);
      af[mi] = *reinterpret_cast<const short8*>(&As[row * 32 + ch * 8]);
    }
#pragma unroll
    for (int ni = 0; ni < 4; ++ni) {
      int row = wc * 64 + ni * 16 + ml;
      int ch = quad ^ ((row >> 1) & 3);
      bfr[ni] = *reinterpret_cast<const short8*>(&Bs[row * 32 + ch * 8]);
    }
#pragma unroll
    for (int mi = 0; mi < 4; ++mi)
#pragma unroll
      for (int ni = 0; ni < 4; ++ni)
        acc[mi][ni] = __builtin_amdgcn_mfma_f32_16x16x32_bf16(af[mi], bfr[ni], acc[mi][ni], 0, 0, 0);
  }

#pragma unroll
  for (int mi = 0; mi < 4; ++mi) {
#pragma unroll
    for (int ni = 0; ni < 4; ++ni) {
#pragma unroll
      for (int r = 0; r < 4; ++r) {
        int row = m0 + wr * 64 + mi * 16 + quad * 4 + r;
        int col = n0 + wc * 64 + ni * 16 + ml;
        float v = acc[mi][ni][r];
        if (mode == 1) {
          out[(size_t)row * N + col] = v;
        } else {
          int b = row >> 11, s = row & (S_LEN - 1);
          if (col < NQ) {
            int h = col >> 7, d = col & 127;
            Qb[((size_t)((b * NH + h) * S_LEN + s)) * HD + d] = f2b(v);
          } else if (col < NQ + NKVD) {
            int cc = col - NQ; int h = cc >> 7, d = cc & 127;
            Kb[((size_t)((b * NKV + h) * S_LEN + s)) * HD + d] = f2b(v);
          } else {
            int cc = col - NQ - NKVD; int h = cc >> 7, d = cc & 127;
            Vt[((size_t)((b * NKV + h) * HD + d)) * S_LEN + s] = f2b(v);
          }
        }
      }
    }
  }
}

// ---------------- RoPE in-place ----------------
__global__ __launch_bounds__(256) void rope_ip(u16* __restrict__ X, int npairs) {
  int idx = blockIdx.x * 256 + threadIdx.x;
  if (idx >= npairs) return;
  int i = idx & 63;
  int s = (idx >> 6) & (S_LEN - 1);
  float inv = __expf(-0.2050369278939421f * (float)i);
  float ang = (float)s * inv;
  float sn, cs;
  sincosf(ang, &sn, &cs);
  ushort2 pr = reinterpret_cast<ushort2*>(X)[idx];
  float a = b2f(pr.x), b = b2f(pr.y);
  ushort2 o;
  o.x = f2b(a * cs - b * sn);
  o.y = f2b(a * sn + b * cs);
  reinterpret_cast<ushort2*>(X)[idx] = o;
}

// ---------------- flash attention (S^T orientation, fixed-max, DMA staging) ----------------
__global__ __launch_bounds__(256, 3) void flash(const u16* __restrict__ Qb,
                                                const u16* __restrict__ Kb,
                                                const u16* __restrict__ Vt,
                                                u16* __restrict__ AO) {
  __shared__ __align__(16) u16 Ks[64 * 128];   // [row k][chunk'=chunk^ (row&15)], 16 chunks
  __shared__ __align__(16) u16 Vs[128 * 64];   // [row d][chunk'=chunk^(row&7)], 8 chunks
  __shared__ __align__(16) u16 Ps[4 * 16 * 80];  // per-wave [q=16][k=64 pad->80]

  int tid  = threadIdx.x;
  int lane = tid & 63, w = tid >> 6;
  int ml   = lane & 15, quad = lane >> 4;
  int q_tile = blockIdx.x, h = blockIdx.y, b = blockIdx.z;
  int hkv = h >> 2;
  int q0  = q_tile * 64;
  const u16* Qh = Qb + ((size_t)(b * NH + h) * S_LEN) * HD;
  const u16* Kh = Kb + ((size_t)(b * NKV + hkv) * S_LEN) * HD;
  const u16* Vh = Vt + ((size_t)(b * NKV + hkv) * HD) * S_LEN;
  u16* Pw = Ps + w * 16 * 80;

  // hoist Q B-fragments (lane = q row, quad packs k)
  short8 qf[4];
#pragma unroll
  for (int ks = 0; ks < 4; ++ks)
    qf[ks] = *reinterpret_cast<const short8*>(
        Qh + (size_t)(q0 + w * 16 + ml) * HD + ks * 32 + quad * 8);

  short8 ones8;
  {
    u16 one_b = 0x3f80;
#pragma unroll
    for (int j = 0; j < 8; ++j) ones8[j] = (short)one_b;
  }

  f32x4 o[8] = {};
  f32x4 o9 = {};
  const float SC = 0.12751745f;  // (1/sqrt(128)) * log2(e)
  const float BIAS = 18.0f;

  int qg = q0 + w * 16 + ml;
  int ntile = q_tile + 1;
  for (int it = 0; it < ntile; ++it) {
    int kv0 = it * 64;
    __syncthreads();
    // stage K tile (64 x 128) and V tile (128 x 64) via DMA, swizzled
#pragma unroll
    for (int p = 0; p < 4; ++p) {
      int slot = w * 256 + p * 64 + lane;
      int krow = slot >> 4, kch = slot & 15;
      int ksrc = kch ^ (krow & 15);
      g2l16(Kh + (size_t)(kv0 + krow) * HD + ksrc * 8, &Ks[(w * 256 + p * 64) * 8]);
      int vrow = slot >> 3, vch = slot & 7;
      int vsrc = vch ^ (vrow & 7);
      g2l16(Vh + (size_t)vrow * S_LEN + kv0 + vsrc * 8, &Vs[(w * 256 + p * 64) * 8]);
    }
    __syncthreads();

    // S^T tiles: mfma(A=K rows, B=Q rows) -> C[k][q], col=q=ml, row=k=quad*4+r
    f32x4 st[4] = {};
#pragma unroll
    for (int ks = 0; ks < 4; ++ks) {
#pragma unroll
      for (int nt = 0; nt < 4; ++nt) {
        int row = nt * 16 + ml;
        int ch = ((ks << 2) | quad) ^ ml;
        short8 kf = *reinterpret_cast<const short8*>(&Ks[row * 128 + ch * 8]);
        st[nt] = __builtin_amdgcn_mfma_f32_16x16x32_bf16(kf, qf[ks], st[nt], 0, 0, 0);
      }
    }

    bool diag = (it == q_tile);
#pragma unroll
    for (int nt = 0; nt < 4; ++nt) {
      float p0 = exp2f(fmaf(st[nt][0], SC, -BIAS));
      float p1 = exp2f(fmaf(st[nt][1], SC, -BIAS));
      float p2 = exp2f(fmaf(st[nt][2], SC, -BIAS));
      float p3 = exp2f(fmaf(st[nt][3], SC, -BIAS));
      if (diag) {
        int kg = kv0 + nt * 16 + quad * 4;
        if (kg + 0 > qg) p0 = 0.f;
        if (kg + 1 > qg) p1 = 0.f;
        if (kg + 2 > qg) p2 = 0.f;
        if (kg + 3 > qg) p3 = 0.f;
      }
      uint2 pk;
      pk.x = (unsigned)f2b(p0) | ((unsigned)f2b(p1) << 16);
      pk.y = (unsigned)f2b(p2) | ((unsigned)f2b(p3) << 16);
      *reinterpret_cast<uint2*>(&Pw[ml * 80 + nt * 16 + quad * 4]) = pk;
    }
    // wave-private Ps: no barrier needed (lgkmcnt wait auto-inserted)

#pragma unroll
    for (int ks2 = 0; ks2 < 2; ++ks2) {
      short8 pf = *reinterpret_cast<const short8*>(&Pw[ml * 80 + ks2 * 32 + quad * 8]);
#pragma unroll
      for (int dt = 0; dt < 8; ++dt) {
        int row = dt * 16 + ml;
        int ch = ((ks2 << 2) | quad) ^ (ml & 7);
        short8 vf = *reinterpret_cast<const short8*>(&Vs[row * 64 + ch * 8]);
        o[dt] = __builtin_amdgcn_mfma_f32_16x16x32_bf16(pf, vf, o[dt], 0, 0, 0);
      }
      o9 = __builtin_amdgcn_mfma_f32_16x16x32_bf16(pf, ones8, o9, 0, 0, 0);
    }
  }

  size_t row_base = (size_t)(b * S_LEN + q0 + w * 16 + quad * 4);
#pragma unroll
  for (int r = 0; r < 4; ++r) {
    float inv_l = 1.0f / o9[r];
#pragma unroll
    for (int dt = 0; dt < 8; ++dt) {
      int col = h * HD + dt * 16 + ml;
      AO[(row_base + r) * (size_t)DIM + col] = f2b(o[dt][r] * inv_l);
    }
  }
}

extern "C" void kernel_launch(void* const* d_in, const int* in_sizes, int n_in,
                              void* d_out, int out_size, void* d_ws, size_t ws_size,
                              hipStream_t stream) {
  const float* x  = (const float*)d_in[0];
  const float* wq = (const float*)d_in[1];
  const float* wk = (const float*)d_in[2];
  const float* wv = (const float*)d_in[3];
  const float* wo = (const float*)d_in[4];
  float* out = (float*)d_out;
  char* ws = (char*)d_ws;

  u16* Wqt = (u16*)(ws + 0);          // [4096][4096], later wo^T
  u16* Wkt = (u16*)(ws + 33554432);   // [1024][4096]
  u16* Wvt = (u16*)(ws + 41943040);   // [1024][4096]
  u16* Xb  = (u16*)(ws + 50331648);   // [4096][4096], later AO
  u16* Qb  = (u16*)(ws + 83886080);
  u16* Kb  = (u16*)(ws + 117440512);
  u16* Vt  = (u16*)(ws + 125829120);

  transpose_cast<<<dim3(128, 128), dim3(32, 8), 0, stream>>>(wq, Wqt, 4096, 4096);
  transpose_cast<<<dim3(32, 128),  dim3(32, 8), 0, stream>>>(wk, Wkt, 4096, 1024);
  transpose_cast<<<dim3(32, 128),  dim3(32, 8), 0, stream>>>(wv, Wvt, 4096, 1024);
  cast_x<<<16384, 256, 0, stream>>>(x, Xb, 4194304);

  gemm_bt<<<dim3(48, 32), 256, 0, stream>>>(Xb, Wqt, 6144, 0, nullptr, Qb, Kb, Vt);

  rope_ip<<<32768, 256, 0, stream>>>(Qb, 8388608);
  rope_ip<<<8192, 256, 0, stream>>>(Kb, 2097152);

  transpose_cast<<<dim3(128, 128), dim3(32, 8), 0, stream>>>(wo, Wqt, 4096, 4096);

  flash<<<dim3(32, 32, 2), 256, 0, stream>>>(Qb, Kb, Vt, Xb);

  gemm_bt<<<dim3(32, 32), 256, 0, stream>>>(Xb, Wqt, 4096, 1, out, nullptr, nullptr, nullptr);
}